// Round 4
// baseline (839.037 us; speedup 1.0000x reference)
//
#include <hip/hip_runtime.h>
#include <hip/hip_bf16.h>

#define NU 30000
#define NI 70000
#define NN 100000
#define DD 128
#define NLAYERS 3
#define SLOPE_ 0.01f
#define EPS_ 1e-12f

#define NB 782                 // row buckets of 128 rows
#define AROW 136               // LDS A row stride in ushorts (272B = 17*16B)

typedef __bf16 v8bf __attribute__((ext_vector_type(8)));
typedef float v16f __attribute__((ext_vector_type(16)));
typedef unsigned short ushort_t;

union UB8 { uint4 u; v8bf v; };

__device__ __forceinline__ float bflo(unsigned u) { return __uint_as_float(u << 16); }
__device__ __forceinline__ float bfhi(unsigned u) { return __uint_as_float(u & 0xffff0000u); }

__device__ __forceinline__ unsigned pk2(float a, float b) {
    __hip_bfloat162 h = __float22bfloat162_rn(make_float2(a, b));
    return *reinterpret_cast<unsigned*>(&h);
}
__device__ __forceinline__ uint4 pk8(const float* f) {
    return make_uint4(pk2(f[0], f[1]), pk2(f[2], f[3]), pk2(f[4], f[5]), pk2(f[6], f[7]));
}
__device__ __forceinline__ void unp8(uint4 g, float* f) {
    f[0] = bflo(g.x); f[1] = bfhi(g.x);
    f[2] = bflo(g.y); f[3] = bfhi(g.y);
    f[4] = bflo(g.z); f[5] = bfhi(g.z);
    f[6] = bflo(g.w); f[7] = bfhi(g.w);
}
__device__ __forceinline__ ushort_t f2bf1(float x) {
    __hip_bfloat16 h = __float2bfloat16(x);
    return *reinterpret_cast<ushort_t*>(&h);
}

// ---------------------------------------------------------------- concat ----
__global__ __launch_bounds__(256) void k_concat_bf(const float* __restrict__ u,
                                                   const float* __restrict__ it,
                                                   ushort_t* __restrict__ fb) {
    int idx = blockIdx.x * 256 + threadIdx.x;
    if (idx >= NN * DD / 8) return;
    size_t base = (size_t)idx * 8;
    const float* src = (base < (size_t)NU * DD) ? (u + base) : (it + base - (size_t)NU * DD);
    float f[8];
    float4 a = *(const float4*)src;
    float4 b = *(const float4*)(src + 4);
    f[0] = a.x; f[1] = a.y; f[2] = a.z; f[3] = a.w;
    f[4] = b.x; f[5] = b.y; f[6] = b.z; f[7] = b.w;
    *(uint4*)(fb + base) = pk8(f);
}

// ---------------------------------------------------------------- zero ------
__global__ __launch_bounds__(256) void k_zero(float4* __restrict__ p, int n4) {
    int i = blockIdx.x * 256 + threadIdx.x;
    if (i < n4) p[i] = make_float4(0.f, 0.f, 0.f, 0.f);
}

// ---------------------------------------------------------------- dot -------
__global__ __launch_bounds__(256) void k_dot(const ushort_t* __restrict__ fb,
                                             const int* __restrict__ uIdx,
                                             const int* __restrict__ iIdx,
                                             float* __restrict__ out,
                                             int batch, int accum) {
    int b = blockIdx.x * 4 + (threadIdx.x >> 6);
    if (b >= batch) return;
    int lane = threadIdx.x & 63;
    unsigned ua = *(const unsigned*)(fb + (size_t)uIdx[b] * DD + lane * 2);
    unsigned ib = *(const unsigned*)(fb + (size_t)(iIdx[b] + NU) * DD + lane * 2);
    float s = bflo(ua) * bflo(ib) + bfhi(ua) * bfhi(ib);
#pragma unroll
    for (int m = 32; m; m >>= 1) s += __shfl_xor(s, m, 64);
    if (lane == 0) out[b] = accum ? out[b] + s : s;
}

// ------------------------------------------------------- bucketed CSR build -
__global__ __launch_bounds__(256) void k_bhist(const int* __restrict__ rows,
                                               int* __restrict__ bcnt, int nnz) {
    int e = blockIdx.x * 256 + threadIdx.x;
    if (e < nnz) atomicAdd(&bcnt[rows[e] >> 7], 1);
}

// scan 1024 padded bucket counts (single block, 256 threads)
__global__ __launch_bounds__(256) void k_bscan(const int4* __restrict__ bcnt4,
                                               int* __restrict__ bbase,
                                               int* __restrict__ bfill) {
    int t = threadIdx.x;
    int4 c = bcnt4[t];
    int tsum = c.x + c.y + c.z + c.w;
    int incl = tsum;
#pragma unroll
    for (int m = 1; m < 64; m <<= 1) {
        int o = __shfl_up(incl, m, 64);
        if ((t & 63) >= m) incl += o;
    }
    __shared__ int wsum[4];
    if ((t & 63) == 63) wsum[t >> 6] = incl;
    __syncthreads();
    int off = 0;
    for (int i = 0; i < (t >> 6); ++i) off += wsum[i];
    int excl = off + incl - tsum;
    int4 rp;
    rp.x = excl;
    rp.y = rp.x + c.x;
    rp.z = rp.y + c.y;
    rp.w = rp.z + c.z;
    *(int4*)(bbase + t * 4) = rp;
    *(int4*)(bfill + t * 4) = rp;
}

// scatter to bucket (row low bits packed into col high bits)
__global__ __launch_bounds__(256) void k_bscatter(const int* __restrict__ rows,
                                                  const int* __restrict__ cols,
                                                  const float* __restrict__ vals,
                                                  int* __restrict__ bfill,
                                                  int2* __restrict__ bedges, int nnz) {
    int e = blockIdx.x * 256 + threadIdx.x;
    if (e >= nnz) return;
    int r = rows[e];
    int p = atomicAdd(&bfill[r >> 7], 1);
    bedges[p] = make_int2(((r & 127) << 20) | cols[e], __float_as_int(vals[e]));
}

// per-bucket counting sort -> final CSR edges + rowPtr
__global__ __launch_bounds__(256) void k_csort(const int* __restrict__ bbase,
                                               const int2* __restrict__ bedges,
                                               int2* __restrict__ edges,
                                               int* __restrict__ rowPtr, int nnz) {
    __shared__ int cntS[128];
    __shared__ int fillS[128];
    __shared__ int wtot;
    int b = blockIdx.x, t = threadIdx.x;
    int s0 = bbase[b], s1 = bbase[b + 1];
    if (t < 128) cntS[t] = 0;
    __syncthreads();
    for (int i = s0 + t; i < s1; i += 256) atomicAdd(&cntS[bedges[i].x >> 20], 1);
    __syncthreads();
    int v = 0, incl = 0;
    if (t < 128) {
        v = cntS[t];
        incl = v;
#pragma unroll
        for (int m = 1; m < 64; m <<= 1) {
            int o = __shfl_up(incl, m, 64);
            if ((t & 63) >= m) incl += o;
        }
        if (t == 63) wtot = incl;
    }
    __syncthreads();
    if (t < 128) {
        int excl = incl - v + ((t >= 64) ? wtot : 0);
        fillS[t] = excl;
        int gr = b * 128 + t;
        if (gr < NN) rowPtr[gr] = s0 + excl;
    }
    if (b == 0 && t == 0) rowPtr[NN] = nnz;
    __syncthreads();
    for (int i = s0 + t; i < s1; i += 256) {
        int2 e = bedges[i];
        int r = e.x >> 20;
        int p = atomicAdd(&fillS[r], 1);
        edges[s0 + p] = make_int2(e.x & 0xFFFFF, e.y);
    }
}

// ---------------------------------------------------------------- wprep -----
// pre-convert [Wlin;Wint] (3 layers) to bf16 MFMA B-fragment order.
// Wb4[id], id = ((layer*2+c)*8+s)*256 + w*64 + lane; elem j: B[k][n],
// k = s*16 + (lane>>5)*8 + j, n = w*32 + (lane&31).
__global__ __launch_bounds__(256) void k_wprep(const float* __restrict__ Wlin,
                                               const float* __restrict__ Wint,
                                               uint4* __restrict__ Wb4) {
    int id = blockIdx.x * 256 + threadIdx.x;   // 0..12287
    int lane = id & 63;
    int w = (id >> 6) & 3;
    int s = (id >> 8) & 7;
    int c = (id >> 11) & 1;
    int l = id >> 12;
    const float* src = (c ? Wint : Wlin) + (size_t)l * DD * DD;
    int n = w * 32 + (lane & 31);
    int k0 = s * 16 + ((lane >> 5) & 1) * 8;
    float f[8];
#pragma unroll
    for (int j = 0; j < 8; ++j) f[j] = src[(size_t)(k0 + j) * DD + n];
    Wb4[id] = pk8(f);
}

// ---------------------------------------------------------------- spmm ------
__global__ __launch_bounds__(256) void k_spmm_bf(const int* __restrict__ rowPtr,
                                                 const int2* __restrict__ edges,
                                                 const ushort_t* __restrict__ fb,
                                                 ushort_t* __restrict__ Lxb) {
    int r = blockIdx.x * 4 + (threadIdx.x >> 6);
    if (r >= NN) return;
    int l = threadIdx.x & 63;
    int q = l >> 4;
    int d0 = (l & 15) * 8;
    int beg = rowPtr[r], end = rowPtr[r + 1];
    float acc[8] = {0.f, 0.f, 0.f, 0.f, 0.f, 0.f, 0.f, 0.f};
    int e = beg + q;
    for (; e + 4 < end; e += 8) {
        int2 p0 = edges[e];
        int2 p1 = edges[e + 4];
        uint4 g0 = *(const uint4*)(fb + (size_t)p0.x * DD + d0);
        uint4 g1 = *(const uint4*)(fb + (size_t)p1.x * DD + d0);
        float v0 = __int_as_float(p0.y), v1 = __int_as_float(p1.y);
        float x0[8], x1[8];
        unp8(g0, x0);
        unp8(g1, x1);
#pragma unroll
        for (int j = 0; j < 8; ++j) acc[j] = fmaf(v0, x0[j], acc[j]);
#pragma unroll
        for (int j = 0; j < 8; ++j) acc[j] = fmaf(v1, x1[j], acc[j]);
    }
    if (e < end) {
        int2 p0 = edges[e];
        uint4 g0 = *(const uint4*)(fb + (size_t)p0.x * DD + d0);
        float v0 = __int_as_float(p0.y);
        float x0[8];
        unp8(g0, x0);
#pragma unroll
        for (int j = 0; j < 8; ++j) acc[j] = fmaf(v0, x0[j], acc[j]);
    }
#pragma unroll
    for (int j = 0; j < 8; ++j) {
        acc[j] += __shfl_xor(acc[j], 16, 64);
        acc[j] += __shfl_xor(acc[j], 32, 64);
    }
    if (l < 16) *(uint4*)(Lxb + (size_t)r * DD + d0) = pk8(acc);
}

// ---------------------------------------------------------------- layer -----
// A = [Lx+f | Lx*f] (Mx256) processed in 2 K-chunks of 128; wave owns 32 cols;
// B from prepacked Wb4; merge-butterfly epilogue with single pnorm barrier.
__global__ __launch_bounds__(256, 4) void k_layer2(const ushort_t* __restrict__ Lxb,
                                                   const uint4* __restrict__ Wb4,
                                                   const float* __restrict__ blin,
                                                   const float* __restrict__ bint,
                                                   ushort_t* __restrict__ fb) {
    __shared__ ushort_t As[128 * AROW];    // 34816 B
    __shared__ float pnormAll[128 * 4];    // 2048 B
    __shared__ float rinvS[128];           // 512 B

    const int t = threadIdx.x;
    const int w = t >> 6;
    const int l = t & 63;
    const int q = l >> 5;
    const int ln = l & 31;
    const int n = w * 32 + ln;
    const int m0 = blockIdx.x * 128;

    const float bias = blin[n] + bint[n];

    v16f acc[4];
#pragma unroll
    for (int mt = 0; mt < 4; ++mt)
#pragma unroll
        for (int i = 0; i < 16; ++i) acc[mt][i] = 0.f;

    for (int c = 0; c < 2; ++c) {
        // ---- stage chunk c of A ----
#pragma unroll
        for (int ii = 0; ii < 8; ++ii) {
            int idx = ii * 256 + t;
            int row = idx >> 4;
            int ch = idx & 15;
            int gm = m0 + row;
            uint4 outv = make_uint4(0, 0, 0, 0);
            if (gm < NN) {
                uint4 gl = *(const uint4*)(Lxb + (size_t)gm * DD + ch * 8);
                uint4 gf = *(const uint4*)(fb + (size_t)gm * DD + ch * 8);
                float a[8], b[8], r[8];
                unp8(gl, a);
                unp8(gf, b);
                if (c == 0) {
#pragma unroll
                    for (int j = 0; j < 8; ++j) r[j] = a[j] + b[j];
                } else {
#pragma unroll
                    for (int j = 0; j < 8; ++j) r[j] = a[j] * b[j];
                }
                outv = pk8(r);
            }
            *(uint4*)&As[row * AROW + ch * 8] = outv;
        }
        __syncthreads();

        // ---- B fragments for this chunk (coalesced from prepack) ----
        UB8 bf[8];
#pragma unroll
        for (int s = 0; s < 8; ++s) bf[s].u = Wb4[c * 2048 + s * 256 + w * 64 + l];

#pragma unroll
        for (int mt = 0; mt < 4; ++mt) {
#pragma unroll
            for (int s = 0; s < 8; ++s) {
                v8bf af = *(const v8bf*)&As[(mt * 32 + ln) * AROW + s * 16 + q * 8];
                acc[mt] = __builtin_amdgcn_mfma_f32_32x32x16_bf16(af, bf[s].v, acc[mt], 0, 0, 0);
            }
        }
        __syncthreads();
    }

    // ---- epilogue: bias + leakyrelu, merge-butterfly sumsq partials ----
#pragma unroll
    for (int mt = 0; mt < 4; ++mt) {
        float r[16];
#pragma unroll
        for (int reg = 0; reg < 16; ++reg) {
            float v = acc[mt][reg] + bias;
            v = (v > 0.f) ? v : SLOPE_ * v;
            acc[mt][reg] = v;
            r[reg] = v * v;
        }
        // merge levels m=1,2,4,8: 16 regs -> 1, lane ln&15 ends with reg=ln&15
#pragma unroll
        for (int lev = 0; lev < 4; ++lev) {
            int m = 1 << lev;
            int cnt = 8 >> lev;
            bool hi = (l & m) != 0;
#pragma unroll
            for (int i = 0; i < 8; ++i) {
                if (i < cnt) {
                    float p = hi ? r[2 * i + 1] : r[2 * i];
                    float qv = hi ? r[2 * i] : r[2 * i + 1];
                    r[i] = p + __shfl_xor(qv, m, 64);
                }
            }
        }
        float tot = r[0] + __shfl_xor(r[0], 16, 64);
        if ((l & 31) < 16) {
            int i = l & 15;
            int row = (i & 3) + ((i >> 2) << 3) + 4 * q;
            pnormAll[(mt * 32 + row) * 4 + w] = tot;
        }
    }
    __syncthreads();
    if (t < 128) {
        float4 p = *(const float4*)&pnormAll[t * 4];
        float tot = p.x + p.y + p.z + p.w;
        rinvS[t] = 1.0f / fmaxf(sqrtf(tot), EPS_);
    }
    __syncthreads();

#pragma unroll
    for (int mt = 0; mt < 4; ++mt) {
#pragma unroll
        for (int reg = 0; reg < 16; ++reg) {
            int row = (reg & 3) + ((reg >> 2) << 3) + 4 * q;
            int gm = m0 + mt * 32 + row;
            if (gm < NN)
                fb[(size_t)gm * DD + n] = f2bf1(acc[mt][reg] * rinvS[mt * 32 + row]);
        }
    }
}

// ---------------------------------------------------------------- launch ----
extern "C" void kernel_launch(void* const* d_in, const int* in_sizes, int n_in,
                              void* d_out, int out_size, void* d_ws, size_t ws_size,
                              hipStream_t stream) {
    const int*   userIdx = (const int*)d_in[0];
    const int*   itemIdx = (const int*)d_in[1];
    const int*   rows    = (const int*)d_in[2];
    const int*   cols    = (const int*)d_in[3];
    const float* vals    = (const float*)d_in[4];
    const float* uE      = (const float*)d_in[5];
    const float* iE      = (const float*)d_in[6];
    const float* Wlin    = (const float*)d_in[7];
    const float* blin    = (const float*)d_in[8];
    const float* Wint    = (const float*)d_in[9];
    const float* bint    = (const float*)d_in[10];
    float* out = (float*)d_out;

    const int batch = in_sizes[0];
    const int nnz   = in_sizes[2];

    // ---- workspace layout ----
    ushort_t* featb = (ushort_t*)d_ws;                       // 25.6 MB
    ushort_t* Lxb   = featb + (size_t)NN * DD;               // 25.6 MB
    uint4* Wb4      = (uint4*)(Lxb + (size_t)NN * DD);       // 196 KB
    int2*  bedges   = (int2*)(Wb4 + 12288);                  // 8 MB
    int2*  edges    = bedges + nnz;                          // 8 MB
    int*   bcnt     = (int*)(edges + nnz);                   // 1024
    int*   bbase    = bcnt + 1024;                           // 1024
    int*   bfill    = bbase + 1024;                          // 1024
    int*   rowPtr   = bfill + 1024;                          // NN+1

    // features = bf16(concat(uEmbd, iEmbd))
    k_concat_bf<<<(NN * DD / 8 + 255) / 256, 256, 0, stream>>>(uE, iE, featb);

    // W prepack (all layers)
    k_wprep<<<48, 256, 0, stream>>>(Wlin, Wint, Wb4);

    // ---- bucketed CSR build ----
    k_zero<<<1, 256, 0, stream>>>((float4*)bcnt, 256);
    k_bhist<<<(nnz + 255) / 256, 256, 0, stream>>>(rows, bcnt, nnz);
    k_bscan<<<1, 256, 0, stream>>>((const int4*)bcnt, bbase, bfill);
    k_bscatter<<<(nnz + 255) / 256, 256, 0, stream>>>(rows, cols, vals, bfill, bedges, nnz);
    k_csort<<<NB, 256, 0, stream>>>(bbase, bedges, edges, rowPtr, nnz);

    // layer-0 dot
    k_dot<<<(batch + 3) / 4, 256, 0, stream>>>(featb, userIdx, itemIdx, out, batch, 0);

    for (int l = 0; l < NLAYERS; ++l) {
        k_spmm_bf<<<(NN + 3) / 4, 256, 0, stream>>>(rowPtr, edges, featb, Lxb);
        k_layer2<<<(NN + 127) / 128, 256, 0, stream>>>(
            Lxb, Wb4 + (size_t)l * 4096,
            blin + (size_t)l * DD, bint + (size_t)l * DD,
            featb);
        k_dot<<<(batch + 3) / 4, 256, 0, stream>>>(featb, userIdx, itemIdx, out, batch, 1);
    }
}

// Round 5
// 523.962 us; speedup vs baseline: 1.6013x; 1.6013x over previous
//
#include <hip/hip_runtime.h>
#include <hip/hip_bf16.h>

#define NU 30000
#define NI 70000
#define NN 100000
#define DD 128
#define NLAYERS 3
#define SLOPE_ 0.01f
#define EPS_ 1e-12f

#define NB 782                 // row buckets of 128 rows
#define NBKT 1024              // padded bucket count (pow2)
#define NBLK 256               // scatter blocks
#define AROW 136               // LDS A row stride in ushorts (272B = 17*16B)

typedef __bf16 v8bf __attribute__((ext_vector_type(8)));
typedef float v16f __attribute__((ext_vector_type(16)));
typedef unsigned short ushort_t;

union UB8 { uint4 u; v8bf v; };

__device__ __forceinline__ float bflo(unsigned u) { return __uint_as_float(u << 16); }
__device__ __forceinline__ float bfhi(unsigned u) { return __uint_as_float(u & 0xffff0000u); }

__device__ __forceinline__ unsigned pk2(float a, float b) {
    __hip_bfloat162 h = __float22bfloat162_rn(make_float2(a, b));
    return *reinterpret_cast<unsigned*>(&h);
}
__device__ __forceinline__ uint4 pk8(const float* f) {
    return make_uint4(pk2(f[0], f[1]), pk2(f[2], f[3]), pk2(f[4], f[5]), pk2(f[6], f[7]));
}
__device__ __forceinline__ void unp8(uint4 g, float* f) {
    f[0] = bflo(g.x); f[1] = bfhi(g.x);
    f[2] = bflo(g.y); f[3] = bfhi(g.y);
    f[4] = bflo(g.z); f[5] = bfhi(g.z);
    f[6] = bflo(g.w); f[7] = bfhi(g.w);
}
__device__ __forceinline__ ushort_t f2bf1(float x) {
    __hip_bfloat16 h = __float2bfloat16(x);
    return *reinterpret_cast<ushort_t*>(&h);
}

// ---------------------------------------------------------------- concat ----
__global__ __launch_bounds__(256) void k_concat_bf(const float* __restrict__ u,
                                                   const float* __restrict__ it,
                                                   ushort_t* __restrict__ fb) {
    int idx = blockIdx.x * 256 + threadIdx.x;
    if (idx >= NN * DD / 8) return;
    size_t base = (size_t)idx * 8;
    const float* src = (base < (size_t)NU * DD) ? (u + base) : (it + base - (size_t)NU * DD);
    float f[8];
    float4 a = *(const float4*)src;
    float4 b = *(const float4*)(src + 4);
    f[0] = a.x; f[1] = a.y; f[2] = a.z; f[3] = a.w;
    f[4] = b.x; f[5] = b.y; f[6] = b.z; f[7] = b.w;
    *(uint4*)(fb + base) = pk8(f);
}

// ---------------------------------------------------------------- dot -------
__global__ __launch_bounds__(256) void k_dot(const ushort_t* __restrict__ fb,
                                             const int* __restrict__ uIdx,
                                             const int* __restrict__ iIdx,
                                             float* __restrict__ out,
                                             int batch, int accum) {
    int b = blockIdx.x * 4 + (threadIdx.x >> 6);
    if (b >= batch) return;
    int lane = threadIdx.x & 63;
    unsigned ua = *(const unsigned*)(fb + (size_t)uIdx[b] * DD + lane * 2);
    unsigned ib = *(const unsigned*)(fb + (size_t)(iIdx[b] + NU) * DD + lane * 2);
    float s = bflo(ua) * bflo(ib) + bfhi(ua) * bfhi(ib);
#pragma unroll
    for (int m = 32; m; m >>= 1) s += __shfl_xor(s, m, 64);
    if (lane == 0) out[b] = accum ? out[b] + s : s;
}

// ------------------------------------------------- contention-free CSR build
// pass 1: per-block LDS histograms -> ghist[bucket][block] (bucket-major)
__global__ __launch_bounds__(256) void k_lhist(const int* __restrict__ rows,
                                               int* __restrict__ ghist,
                                               int nnz, int epb) {
    __shared__ int h[NBKT];
    int t = threadIdx.x, b = blockIdx.x;
#pragma unroll
    for (int i = 0; i < 4; ++i) h[t + 256 * i] = 0;
    __syncthreads();
    int e0 = b * epb, e1 = min(e0 + epb, nnz);
    for (int e = e0 + t; e < e1; e += 256) atomicAdd(&h[rows[e] >> 7], 1);
    __syncthreads();
#pragma unroll
    for (int i = 0; i < 4; ++i) {
        int bkt = t + 256 * i;
        ghist[bkt * NBLK + b] = h[bkt];
    }
}

// pass 2: exclusive scan of 256K ints, single block; 1024 ints per thread
__global__ __launch_bounds__(256) void k_gscan(int* __restrict__ ghist) {
    int t = threadIdx.x;
    const int CH = NBKT * NBLK / 256;   // 1024
    int base = t * CH;
    int s = 0;
    for (int i = 0; i < CH; i += 4) {
        int4 c = *(const int4*)(ghist + base + i);
        s += c.x + c.y + c.z + c.w;
    }
    int incl = s;
#pragma unroll
    for (int m = 1; m < 64; m <<= 1) {
        int o = __shfl_up(incl, m, 64);
        if ((t & 63) >= m) incl += o;
    }
    __shared__ int wsum[4];
    if ((t & 63) == 63) wsum[t >> 6] = incl;
    __syncthreads();
    int off = 0;
    for (int i = 0; i < (t >> 6); ++i) off += wsum[i];
    int run = off + incl - s;          // exclusive prefix for this chunk
    for (int i = 0; i < CH; i += 4) {
        int4 c = *(const int4*)(ghist + base + i);
        int4 o;
        o.x = run;
        o.y = o.x + c.x;
        o.z = o.y + c.y;
        o.w = o.z + c.z;
        run = o.w + c.w;
        *(int4*)(ghist + base + i) = o;
    }
}

// pass 3: replay edges, rank via LDS atomics, write to scanned position
__global__ __launch_bounds__(256) void k_sscatter(const int* __restrict__ rows,
                                                  const int* __restrict__ cols,
                                                  const float* __restrict__ vals,
                                                  const int* __restrict__ ghist,
                                                  int2* __restrict__ bedges,
                                                  int nnz, int epb) {
    __shared__ int base[NBKT];
    __shared__ int h[NBKT];
    int t = threadIdx.x, b = blockIdx.x;
#pragma unroll
    for (int i = 0; i < 4; ++i) {
        int bkt = t + 256 * i;
        base[bkt] = ghist[bkt * NBLK + b];
        h[bkt] = 0;
    }
    __syncthreads();
    int e0 = b * epb, e1 = min(e0 + epb, nnz);
    for (int e = e0 + t; e < e1; e += 256) {
        int r = rows[e];
        int bkt = r >> 7;
        int rank = atomicAdd(&h[bkt], 1);
        bedges[base[bkt] + rank] = make_int2(((r & 127) << 20) | cols[e],
                                             __float_as_int(vals[e]));
    }
}

// pass 4: per-bucket counting sort by row -> final CSR edges + rowPtr
__global__ __launch_bounds__(256) void k_csort(const int* __restrict__ ghist,
                                               const int2* __restrict__ bedges,
                                               int2* __restrict__ edges,
                                               int* __restrict__ rowPtr, int nnz) {
    __shared__ int cntS[128];
    __shared__ int fillS[128];
    __shared__ int wtot;
    int b = blockIdx.x, t = threadIdx.x;
    int s0 = ghist[b * NBLK];
    int s1 = ghist[(b + 1) * NBLK];    // buckets >= NB are empty -> == nnz at NB
    if (t < 128) cntS[t] = 0;
    __syncthreads();
    for (int i = s0 + t; i < s1; i += 256) atomicAdd(&cntS[bedges[i].x >> 20], 1);
    __syncthreads();
    int v = 0, incl = 0;
    if (t < 128) {
        v = cntS[t];
        incl = v;
#pragma unroll
        for (int m = 1; m < 64; m <<= 1) {
            int o = __shfl_up(incl, m, 64);
            if ((t & 63) >= m) incl += o;
        }
        if (t == 63) wtot = incl;
    }
    __syncthreads();
    if (t < 128) {
        int excl = incl - v + ((t >= 64) ? wtot : 0);
        fillS[t] = excl;
        int gr = b * 128 + t;
        if (gr < NN) rowPtr[gr] = s0 + excl;
    }
    if (b == 0 && t == 0) rowPtr[NN] = nnz;
    __syncthreads();
    for (int i = s0 + t; i < s1; i += 256) {
        int2 e = bedges[i];
        int r = e.x >> 20;
        int p = atomicAdd(&fillS[r], 1);
        edges[s0 + p] = make_int2(e.x & 0xFFFFF, e.y);
    }
}

// ---------------------------------------------------------------- wprep -----
__global__ __launch_bounds__(256) void k_wprep(const float* __restrict__ Wlin,
                                               const float* __restrict__ Wint,
                                               uint4* __restrict__ Wb4) {
    int id = blockIdx.x * 256 + threadIdx.x;   // 0..12287
    int lane = id & 63;
    int w = (id >> 6) & 3;
    int s = (id >> 8) & 7;
    int c = (id >> 11) & 1;
    int l = id >> 12;
    const float* src = (c ? Wint : Wlin) + (size_t)l * DD * DD;
    int n = w * 32 + (lane & 31);
    int k0 = s * 16 + ((lane >> 5) & 1) * 8;
    float f[8];
#pragma unroll
    for (int j = 0; j < 8; ++j) f[j] = src[(size_t)(k0 + j) * DD + n];
    Wb4[id] = pk8(f);
}

// ---------------------------------------------------------------- spmm ------
__global__ __launch_bounds__(256) void k_spmm_bf(const int* __restrict__ rowPtr,
                                                 const int2* __restrict__ edges,
                                                 const ushort_t* __restrict__ fb,
                                                 ushort_t* __restrict__ Lxb) {
    int r = blockIdx.x * 4 + (threadIdx.x >> 6);
    if (r >= NN) return;
    int l = threadIdx.x & 63;
    int q = l >> 4;
    int d0 = (l & 15) * 8;
    int beg = rowPtr[r], end = rowPtr[r + 1];
    float acc[8] = {0.f, 0.f, 0.f, 0.f, 0.f, 0.f, 0.f, 0.f};
    int e = beg + q;
    for (; e + 4 < end; e += 8) {
        int2 p0 = edges[e];
        int2 p1 = edges[e + 4];
        uint4 g0 = *(const uint4*)(fb + (size_t)p0.x * DD + d0);
        uint4 g1 = *(const uint4*)(fb + (size_t)p1.x * DD + d0);
        float v0 = __int_as_float(p0.y), v1 = __int_as_float(p1.y);
        float x0[8], x1[8];
        unp8(g0, x0);
        unp8(g1, x1);
#pragma unroll
        for (int j = 0; j < 8; ++j) acc[j] = fmaf(v0, x0[j], acc[j]);
#pragma unroll
        for (int j = 0; j < 8; ++j) acc[j] = fmaf(v1, x1[j], acc[j]);
    }
    if (e < end) {
        int2 p0 = edges[e];
        uint4 g0 = *(const uint4*)(fb + (size_t)p0.x * DD + d0);
        float v0 = __int_as_float(p0.y);
        float x0[8];
        unp8(g0, x0);
#pragma unroll
        for (int j = 0; j < 8; ++j) acc[j] = fmaf(v0, x0[j], acc[j]);
    }
#pragma unroll
    for (int j = 0; j < 8; ++j) {
        acc[j] += __shfl_xor(acc[j], 16, 64);
        acc[j] += __shfl_xor(acc[j], 32, 64);
    }
    if (l < 16) *(uint4*)(Lxb + (size_t)r * DD + d0) = pk8(acc);
}

// ---------------------------------------------------------------- layer -----
__global__ __launch_bounds__(256, 3) void k_layer2(const ushort_t* __restrict__ Lxb,
                                                   const uint4* __restrict__ Wb4,
                                                   const float* __restrict__ blin,
                                                   const float* __restrict__ bint,
                                                   ushort_t* __restrict__ fb) {
    __shared__ ushort_t As[128 * AROW];    // 34816 B
    __shared__ float pnormAll[128 * 4];    // 2048 B
    __shared__ float rinvS[128];           // 512 B

    const int t = threadIdx.x;
    const int w = t >> 6;
    const int l = t & 63;
    const int q = l >> 5;
    const int ln = l & 31;
    const int n = w * 32 + ln;
    const int m0 = blockIdx.x * 128;

    const float bias = blin[n] + bint[n];

    v16f acc[4];
#pragma unroll
    for (int mt = 0; mt < 4; ++mt)
#pragma unroll
        for (int i = 0; i < 16; ++i) acc[mt][i] = 0.f;

    for (int c = 0; c < 2; ++c) {
#pragma unroll
        for (int ii = 0; ii < 8; ++ii) {
            int idx = ii * 256 + t;
            int row = idx >> 4;
            int ch = idx & 15;
            int gm = m0 + row;
            uint4 outv = make_uint4(0, 0, 0, 0);
            if (gm < NN) {
                uint4 gl = *(const uint4*)(Lxb + (size_t)gm * DD + ch * 8);
                uint4 gf = *(const uint4*)(fb + (size_t)gm * DD + ch * 8);
                float a[8], b[8], r[8];
                unp8(gl, a);
                unp8(gf, b);
                if (c == 0) {
#pragma unroll
                    for (int j = 0; j < 8; ++j) r[j] = a[j] + b[j];
                } else {
#pragma unroll
                    for (int j = 0; j < 8; ++j) r[j] = a[j] * b[j];
                }
                outv = pk8(r);
            }
            *(uint4*)&As[row * AROW + ch * 8] = outv;
        }
        __syncthreads();

        UB8 bf[8];
#pragma unroll
        for (int s = 0; s < 8; ++s) bf[s].u = Wb4[c * 2048 + s * 256 + w * 64 + l];

#pragma unroll
        for (int mt = 0; mt < 4; ++mt) {
#pragma unroll
            for (int s = 0; s < 8; ++s) {
                v8bf af = *(const v8bf*)&As[(mt * 32 + ln) * AROW + s * 16 + q * 8];
                acc[mt] = __builtin_amdgcn_mfma_f32_32x32x16_bf16(af, bf[s].v, acc[mt], 0, 0, 0);
            }
        }
        __syncthreads();
    }

#pragma unroll
    for (int mt = 0; mt < 4; ++mt) {
        float r[16];
#pragma unroll
        for (int reg = 0; reg < 16; ++reg) {
            float v = acc[mt][reg] + bias;
            v = (v > 0.f) ? v : SLOPE_ * v;
            acc[mt][reg] = v;
            r[reg] = v * v;
        }
#pragma unroll
        for (int lev = 0; lev < 4; ++lev) {
            int m = 1 << lev;
            int cnt = 8 >> lev;
            bool hi = (l & m) != 0;
#pragma unroll
            for (int i = 0; i < 8; ++i) {
                if (i < cnt) {
                    float p = hi ? r[2 * i + 1] : r[2 * i];
                    float qv = hi ? r[2 * i] : r[2 * i + 1];
                    r[i] = p + __shfl_xor(qv, m, 64);
                }
            }
        }
        float tot = r[0] + __shfl_xor(r[0], 16, 64);
        if ((l & 31) < 16) {
            int i = l & 15;
            int row = (i & 3) + ((i >> 2) << 3) + 4 * q;
            pnormAll[(mt * 32 + row) * 4 + w] = tot;
        }
    }
    __syncthreads();
    if (t < 128) {
        float4 p = *(const float4*)&pnormAll[t * 4];
        float tot = p.x + p.y + p.z + p.w;
        rinvS[t] = 1.0f / fmaxf(sqrtf(tot), EPS_);
    }
    __syncthreads();

#pragma unroll
    for (int mt = 0; mt < 4; ++mt) {
#pragma unroll
        for (int reg = 0; reg < 16; ++reg) {
            int row = (reg & 3) + ((reg >> 2) << 3) + 4 * q;
            int gm = m0 + mt * 32 + row;
            if (gm < NN)
                fb[(size_t)gm * DD + n] = f2bf1(acc[mt][reg] * rinvS[mt * 32 + row]);
        }
    }
}

// ---------------------------------------------------------------- launch ----
extern "C" void kernel_launch(void* const* d_in, const int* in_sizes, int n_in,
                              void* d_out, int out_size, void* d_ws, size_t ws_size,
                              hipStream_t stream) {
    const int*   userIdx = (const int*)d_in[0];
    const int*   itemIdx = (const int*)d_in[1];
    const int*   rows    = (const int*)d_in[2];
    const int*   cols    = (const int*)d_in[3];
    const float* vals    = (const float*)d_in[4];
    const float* uE      = (const float*)d_in[5];
    const float* iE      = (const float*)d_in[6];
    const float* Wlin    = (const float*)d_in[7];
    const float* blin    = (const float*)d_in[8];
    const float* Wint    = (const float*)d_in[9];
    const float* bint    = (const float*)d_in[10];
    float* out = (float*)d_out;

    const int batch = in_sizes[0];
    const int nnz   = in_sizes[2];
    const int epb   = (nnz + NBLK - 1) / NBLK;

    // ---- workspace layout ----
    ushort_t* featb = (ushort_t*)d_ws;                       // 25.6 MB
    ushort_t* Lxb   = featb + (size_t)NN * DD;               // 25.6 MB
    uint4* Wb4      = (uint4*)(Lxb + (size_t)NN * DD);       // 196 KB
    int2*  bedges   = (int2*)(Wb4 + 12288);                  // 8 MB
    int2*  edges    = bedges + nnz;                          // 8 MB
    int*   ghist    = (int*)(edges + nnz);                   // 1 MB (1024*256)
    int*   rowPtr   = ghist + NBKT * NBLK;                   // NN+1

    k_concat_bf<<<(NN * DD / 8 + 255) / 256, 256, 0, stream>>>(uE, iE, featb);
    k_wprep<<<48, 256, 0, stream>>>(Wlin, Wint, Wb4);

    // ---- contention-free CSR build ----
    k_lhist<<<NBLK, 256, 0, stream>>>(rows, ghist, nnz, epb);
    k_gscan<<<1, 256, 0, stream>>>(ghist);
    k_sscatter<<<NBLK, 256, 0, stream>>>(rows, cols, vals, ghist, bedges, nnz, epb);
    k_csort<<<NB, 256, 0, stream>>>(ghist, bedges, edges, rowPtr, nnz);

    k_dot<<<(batch + 3) / 4, 256, 0, stream>>>(featb, userIdx, itemIdx, out, batch, 0);

    for (int l = 0; l < NLAYERS; ++l) {
        k_spmm_bf<<<(NN + 3) / 4, 256, 0, stream>>>(rowPtr, edges, featb, Lxb);
        k_layer2<<<(NN + 127) / 128, 256, 0, stream>>>(
            Lxb, Wb4 + (size_t)l * 4096,
            blin + (size_t)l * DD, bint + (size_t)l * DD,
            featb);
        k_dot<<<(batch + 3) / 4, 256, 0, stream>>>(featb, userIdx, itemIdx, out, batch, 1);
    }
}

// Round 6
// 426.531 us; speedup vs baseline: 1.9671x; 1.2284x over previous
//
#include <hip/hip_runtime.h>
#include <hip/hip_bf16.h>

#define NU 30000
#define NI 70000
#define NN 100000
#define DD 128
#define NLAYERS 3
#define SLOPE_ 0.01f
#define EPS_ 1e-12f

#define NB 782                 // row buckets of 128 rows
#define NBKT 1024              // padded bucket count (pow2)
#define NBLK 256               // scatter blocks
#define AROW 136               // LDS A row stride in ushorts (272B = 17*16B)

typedef __bf16 v8bf __attribute__((ext_vector_type(8)));
typedef float v16f __attribute__((ext_vector_type(16)));
typedef unsigned short ushort_t;

union UB8 { uint4 u; v8bf v; };

__device__ __forceinline__ float bflo(unsigned u) { return __uint_as_float(u << 16); }
__device__ __forceinline__ float bfhi(unsigned u) { return __uint_as_float(u & 0xffff0000u); }

__device__ __forceinline__ unsigned pk2(float a, float b) {
    __hip_bfloat162 h = __float22bfloat162_rn(make_float2(a, b));
    return *reinterpret_cast<unsigned*>(&h);
}
__device__ __forceinline__ uint4 pk8(const float* f) {
    return make_uint4(pk2(f[0], f[1]), pk2(f[2], f[3]), pk2(f[4], f[5]), pk2(f[6], f[7]));
}
__device__ __forceinline__ void unp8(uint4 g, float* f) {
    f[0] = bflo(g.x); f[1] = bfhi(g.x);
    f[2] = bflo(g.y); f[3] = bfhi(g.y);
    f[4] = bflo(g.z); f[5] = bfhi(g.z);
    f[6] = bflo(g.w); f[7] = bfhi(g.w);
}
__device__ __forceinline__ ushort_t f2bf1(float x) {
    __hip_bfloat16 h = __float2bfloat16(x);
    return *reinterpret_cast<ushort_t*>(&h);
}

// ---------------------------------------------------------------- concat ----
__global__ __launch_bounds__(256) void k_concat_bf(const float* __restrict__ u,
                                                   const float* __restrict__ it,
                                                   ushort_t* __restrict__ fb) {
    int idx = blockIdx.x * 256 + threadIdx.x;
    if (idx >= NN * DD / 8) return;
    size_t base = (size_t)idx * 8;
    const float* src = (base < (size_t)NU * DD) ? (u + base) : (it + base - (size_t)NU * DD);
    float f[8];
    float4 a = *(const float4*)src;
    float4 b = *(const float4*)(src + 4);
    f[0] = a.x; f[1] = a.y; f[2] = a.z; f[3] = a.w;
    f[4] = b.x; f[5] = b.y; f[6] = b.z; f[7] = b.w;
    *(uint4*)(fb + base) = pk8(f);
}

// ---------------------------------------------------------------- dot -------
__global__ __launch_bounds__(256) void k_dot(const ushort_t* __restrict__ fb,
                                             const int* __restrict__ uIdx,
                                             const int* __restrict__ iIdx,
                                             float* __restrict__ out,
                                             int batch, int accum) {
    int b = blockIdx.x * 4 + (threadIdx.x >> 6);
    if (b >= batch) return;
    int lane = threadIdx.x & 63;
    unsigned ua = *(const unsigned*)(fb + (size_t)uIdx[b] * DD + lane * 2);
    unsigned ib = *(const unsigned*)(fb + (size_t)(iIdx[b] + NU) * DD + lane * 2);
    float s = bflo(ua) * bflo(ib) + bfhi(ua) * bfhi(ib);
#pragma unroll
    for (int m = 32; m; m >>= 1) s += __shfl_xor(s, m, 64);
    if (lane == 0) out[b] = accum ? out[b] + s : s;
}

// ------------------------------------------------- contention-free CSR build
// pass 1: per-block LDS histograms -> ghist[bucket][block] (bucket-major)
__global__ __launch_bounds__(256) void k_lhist(const int* __restrict__ rows,
                                               int* __restrict__ ghist,
                                               int nnz, int epb) {
    __shared__ int h[NBKT];
    int t = threadIdx.x, b = blockIdx.x;
#pragma unroll
    for (int i = 0; i < 4; ++i) h[t + 256 * i] = 0;
    __syncthreads();
    int e0 = b * epb, e1 = min(e0 + epb, nnz);
    for (int e = e0 + t; e < e1; e += 256) atomicAdd(&h[rows[e] >> 7], 1);
    __syncthreads();
#pragma unroll
    for (int i = 0; i < 4; ++i) {
        int bkt = t + 256 * i;
        ghist[bkt * NBLK + b] = h[bkt];
    }
}

// pass 2a: per-bucket scan of 256 block counts (wave per bucket, in-register)
__global__ __launch_bounds__(256) void k_rscan(int* __restrict__ ghist,
                                               int* __restrict__ btot) {
    int t = threadIdx.x;
    int bkt = blockIdx.x * 4 + (t >> 6);
    int lane = t & 63;
    int* row = ghist + bkt * NBLK;
    int4 c = *(const int4*)(row + lane * 4);
    int s = c.x + c.y + c.z + c.w;
    int incl = s;
#pragma unroll
    for (int m = 1; m < 64; m <<= 1) {
        int o = __shfl_up(incl, m, 64);
        if (lane >= m) incl += o;
    }
    int excl = incl - s;
    int4 o;
    o.x = excl;
    o.y = o.x + c.x;
    o.z = o.y + c.y;
    o.w = o.z + c.z;
    *(int4*)(row + lane * 4) = o;
    if (lane == 63) btot[bkt] = incl;
}

// pass 2b: scan 1024 bucket totals -> bucketBase[0..NBKT]
__global__ __launch_bounds__(256) void k_btscan(const int* __restrict__ btot,
                                                int* __restrict__ bbase) {
    int t = threadIdx.x;
    int4 c = *(const int4*)(btot + t * 4);
    int tsum = c.x + c.y + c.z + c.w;
    int incl = tsum;
#pragma unroll
    for (int m = 1; m < 64; m <<= 1) {
        int o = __shfl_up(incl, m, 64);
        if ((t & 63) >= m) incl += o;
    }
    __shared__ int wsum[4];
    if ((t & 63) == 63) wsum[t >> 6] = incl;
    __syncthreads();
    int off = 0;
    for (int i = 0; i < (t >> 6); ++i) off += wsum[i];
    int excl = off + incl - tsum;
    int4 o;
    o.x = excl;
    o.y = o.x + c.x;
    o.z = o.y + c.y;
    o.w = o.z + c.z;
    *(int4*)(bbase + t * 4) = o;
    if (t == 255) bbase[NBKT] = o.w + c.w;
}

// pass 3: replay edges, rank via LDS atomics, write to scanned position
__global__ __launch_bounds__(256) void k_sscatter(const int* __restrict__ rows,
                                                  const int* __restrict__ cols,
                                                  const float* __restrict__ vals,
                                                  const int* __restrict__ ghist,
                                                  const int* __restrict__ bbase,
                                                  int2* __restrict__ bedges,
                                                  int nnz, int epb) {
    __shared__ int base[NBKT];
    __shared__ int h[NBKT];
    int t = threadIdx.x, b = blockIdx.x;
#pragma unroll
    for (int i = 0; i < 4; ++i) {
        int bkt = t + 256 * i;
        base[bkt] = bbase[bkt] + ghist[bkt * NBLK + b];
        h[bkt] = 0;
    }
    __syncthreads();
    int e0 = b * epb, e1 = min(e0 + epb, nnz);
    for (int e = e0 + t; e < e1; e += 256) {
        int r = rows[e];
        int bkt = r >> 7;
        int rank = atomicAdd(&h[bkt], 1);
        bedges[base[bkt] + rank] = make_int2(((r & 127) << 20) | cols[e],
                                             __float_as_int(vals[e]));
    }
}

// pass 4: per-bucket counting sort by row -> final CSR edges + rowPtr
__global__ __launch_bounds__(256) void k_csort(const int* __restrict__ bbase,
                                               const int2* __restrict__ bedges,
                                               int2* __restrict__ edges,
                                               int* __restrict__ rowPtr, int nnz) {
    __shared__ int cntS[128];
    __shared__ int fillS[128];
    __shared__ int wtot;
    int b = blockIdx.x, t = threadIdx.x;
    int s0 = bbase[b];
    int s1 = bbase[b + 1];
    if (t < 128) cntS[t] = 0;
    __syncthreads();
    for (int i = s0 + t; i < s1; i += 256) atomicAdd(&cntS[bedges[i].x >> 20], 1);
    __syncthreads();
    int v = 0, incl = 0;
    if (t < 128) {
        v = cntS[t];
        incl = v;
#pragma unroll
        for (int m = 1; m < 64; m <<= 1) {
            int o = __shfl_up(incl, m, 64);
            if ((t & 63) >= m) incl += o;
        }
        if (t == 63) wtot = incl;
    }
    __syncthreads();
    if (t < 128) {
        int excl = incl - v + ((t >= 64) ? wtot : 0);
        fillS[t] = excl;
        int gr = b * 128 + t;
        if (gr < NN) rowPtr[gr] = s0 + excl;
    }
    if (b == 0 && t == 0) rowPtr[NN] = nnz;
    __syncthreads();
    for (int i = s0 + t; i < s1; i += 256) {
        int2 e = bedges[i];
        int r = e.x >> 20;
        int p = atomicAdd(&fillS[r], 1);
        edges[s0 + p] = make_int2(e.x & 0xFFFFF, e.y);
    }
}

// ---------------------------------------------------------------- wprep -----
__global__ __launch_bounds__(256) void k_wprep(const float* __restrict__ Wlin,
                                               const float* __restrict__ Wint,
                                               uint4* __restrict__ Wb4) {
    int id = blockIdx.x * 256 + threadIdx.x;   // 0..12287
    int lane = id & 63;
    int w = (id >> 6) & 3;
    int s = (id >> 8) & 7;
    int c = (id >> 11) & 1;
    int l = id >> 12;
    const float* src = (c ? Wint : Wlin) + (size_t)l * DD * DD;
    int n = w * 32 + (lane & 31);
    int k0 = s * 16 + ((lane >> 5) & 1) * 8;
    float f[8];
#pragma unroll
    for (int j = 0; j < 8; ++j) f[j] = src[(size_t)(k0 + j) * DD + n];
    Wb4[id] = pk8(f);
}

// ---------------------------------------------------------------- spmm ------
__global__ __launch_bounds__(256) void k_spmm_bf(const int* __restrict__ rowPtr,
                                                 const int2* __restrict__ edges,
                                                 const ushort_t* __restrict__ fb,
                                                 ushort_t* __restrict__ Lxb) {
    int r = blockIdx.x * 4 + (threadIdx.x >> 6);
    if (r >= NN) return;
    int l = threadIdx.x & 63;
    int q = l >> 4;
    int d0 = (l & 15) * 8;
    int beg = rowPtr[r], end = rowPtr[r + 1];
    float acc[8] = {0.f, 0.f, 0.f, 0.f, 0.f, 0.f, 0.f, 0.f};
    int e = beg + q;
    for (; e + 4 < end; e += 8) {
        int2 p0 = edges[e];
        int2 p1 = edges[e + 4];
        uint4 g0 = *(const uint4*)(fb + (size_t)p0.x * DD + d0);
        uint4 g1 = *(const uint4*)(fb + (size_t)p1.x * DD + d0);
        float v0 = __int_as_float(p0.y), v1 = __int_as_float(p1.y);
        float x0[8], x1[8];
        unp8(g0, x0);
        unp8(g1, x1);
#pragma unroll
        for (int j = 0; j < 8; ++j) acc[j] = fmaf(v0, x0[j], acc[j]);
#pragma unroll
        for (int j = 0; j < 8; ++j) acc[j] = fmaf(v1, x1[j], acc[j]);
    }
    if (e < end) {
        int2 p0 = edges[e];
        uint4 g0 = *(const uint4*)(fb + (size_t)p0.x * DD + d0);
        float v0 = __int_as_float(p0.y);
        float x0[8];
        unp8(g0, x0);
#pragma unroll
        for (int j = 0; j < 8; ++j) acc[j] = fmaf(v0, x0[j], acc[j]);
    }
#pragma unroll
    for (int j = 0; j < 8; ++j) {
        acc[j] += __shfl_xor(acc[j], 16, 64);
        acc[j] += __shfl_xor(acc[j], 32, 64);
    }
    if (l < 16) *(uint4*)(Lxb + (size_t)r * DD + d0) = pk8(acc);
}

// ---------------------------------------------------------------- layer -----
__global__ __launch_bounds__(256, 3) void k_layer2(const ushort_t* __restrict__ Lxb,
                                                   const uint4* __restrict__ Wb4,
                                                   const float* __restrict__ blin,
                                                   const float* __restrict__ bint,
                                                   ushort_t* __restrict__ fb) {
    __shared__ ushort_t As[128 * AROW];    // 34816 B
    __shared__ float pnormAll[128 * 4];    // 2048 B
    __shared__ float rinvS[128];           // 512 B

    const int t = threadIdx.x;
    const int w = t >> 6;
    const int l = t & 63;
    const int q = l >> 5;
    const int ln = l & 31;
    const int n = w * 32 + ln;
    const int m0 = blockIdx.x * 128;

    const float bias = blin[n] + bint[n];

    v16f acc[4];
#pragma unroll
    for (int mt = 0; mt < 4; ++mt)
#pragma unroll
        for (int i = 0; i < 16; ++i) acc[mt][i] = 0.f;

    for (int c = 0; c < 2; ++c) {
#pragma unroll
        for (int ii = 0; ii < 8; ++ii) {
            int idx = ii * 256 + t;
            int row = idx >> 4;
            int ch = idx & 15;
            int gm = m0 + row;
            uint4 outv = make_uint4(0, 0, 0, 0);
            if (gm < NN) {
                uint4 gl = *(const uint4*)(Lxb + (size_t)gm * DD + ch * 8);
                uint4 gf = *(const uint4*)(fb + (size_t)gm * DD + ch * 8);
                float a[8], b[8], r[8];
                unp8(gl, a);
                unp8(gf, b);
                if (c == 0) {
#pragma unroll
                    for (int j = 0; j < 8; ++j) r[j] = a[j] + b[j];
                } else {
#pragma unroll
                    for (int j = 0; j < 8; ++j) r[j] = a[j] * b[j];
                }
                outv = pk8(r);
            }
            *(uint4*)&As[row * AROW + ch * 8] = outv;
        }
        __syncthreads();

        UB8 bf[8];
#pragma unroll
        for (int s = 0; s < 8; ++s) bf[s].u = Wb4[c * 2048 + s * 256 + w * 64 + l];

#pragma unroll
        for (int mt = 0; mt < 4; ++mt) {
#pragma unroll
            for (int s = 0; s < 8; ++s) {
                v8bf af = *(const v8bf*)&As[(mt * 32 + ln) * AROW + s * 16 + q * 8];
                acc[mt] = __builtin_amdgcn_mfma_f32_32x32x16_bf16(af, bf[s].v, acc[mt], 0, 0, 0);
            }
        }
        __syncthreads();
    }

#pragma unroll
    for (int mt = 0; mt < 4; ++mt) {
        float r[16];
#pragma unroll
        for (int reg = 0; reg < 16; ++reg) {
            float v = acc[mt][reg] + bias;
            v = (v > 0.f) ? v : SLOPE_ * v;
            acc[mt][reg] = v;
            r[reg] = v * v;
        }
#pragma unroll
        for (int lev = 0; lev < 4; ++lev) {
            int m = 1 << lev;
            int cnt = 8 >> lev;
            bool hi = (l & m) != 0;
#pragma unroll
            for (int i = 0; i < 8; ++i) {
                if (i < cnt) {
                    float p = hi ? r[2 * i + 1] : r[2 * i];
                    float qv = hi ? r[2 * i] : r[2 * i + 1];
                    r[i] = p + __shfl_xor(qv, m, 64);
                }
            }
        }
        float tot = r[0] + __shfl_xor(r[0], 16, 64);
        if ((l & 31) < 16) {
            int i = l & 15;
            int row = (i & 3) + ((i >> 2) << 3) + 4 * q;
            pnormAll[(mt * 32 + row) * 4 + w] = tot;
        }
    }
    __syncthreads();
    if (t < 128) {
        float4 p = *(const float4*)&pnormAll[t * 4];
        float tot = p.x + p.y + p.z + p.w;
        rinvS[t] = 1.0f / fmaxf(sqrtf(tot), EPS_);
    }
    __syncthreads();

#pragma unroll
    for (int mt = 0; mt < 4; ++mt) {
#pragma unroll
        for (int reg = 0; reg < 16; ++reg) {
            int row = (reg & 3) + ((reg >> 2) << 3) + 4 * q;
            int gm = m0 + mt * 32 + row;
            if (gm < NN)
                fb[(size_t)gm * DD + n] = f2bf1(acc[mt][reg] * rinvS[mt * 32 + row]);
        }
    }
}

// ---------------------------------------------------------------- launch ----
extern "C" void kernel_launch(void* const* d_in, const int* in_sizes, int n_in,
                              void* d_out, int out_size, void* d_ws, size_t ws_size,
                              hipStream_t stream) {
    const int*   userIdx = (const int*)d_in[0];
    const int*   itemIdx = (const int*)d_in[1];
    const int*   rows    = (const int*)d_in[2];
    const int*   cols    = (const int*)d_in[3];
    const float* vals    = (const float*)d_in[4];
    const float* uE      = (const float*)d_in[5];
    const float* iE      = (const float*)d_in[6];
    const float* Wlin    = (const float*)d_in[7];
    const float* blin    = (const float*)d_in[8];
    const float* Wint    = (const float*)d_in[9];
    const float* bint    = (const float*)d_in[10];
    float* out = (float*)d_out;

    const int batch = in_sizes[0];
    const int nnz   = in_sizes[2];
    const int epb   = (nnz + NBLK - 1) / NBLK;

    // ---- workspace layout ----
    ushort_t* featb = (ushort_t*)d_ws;                       // 25.6 MB
    ushort_t* Lxb   = featb + (size_t)NN * DD;               // 25.6 MB
    uint4* Wb4      = (uint4*)(Lxb + (size_t)NN * DD);       // 196 KB
    int2*  bedges   = (int2*)(Wb4 + 12288);                  // 8 MB
    int2*  edges    = bedges + nnz;                          // 8 MB
    int*   ghist    = (int*)(edges + nnz);                   // 1 MB (1024*256)
    int*   btot     = ghist + NBKT * NBLK;                   // 4 KB
    int*   bbase    = btot + NBKT;                           // 4 KB (+1)
    int*   rowPtr   = bbase + NBKT + 4;                      // NN+1

    k_concat_bf<<<(NN * DD / 8 + 255) / 256, 256, 0, stream>>>(uE, iE, featb);
    k_wprep<<<48, 256, 0, stream>>>(Wlin, Wint, Wb4);

    // ---- contention-free CSR build (hierarchical scan) ----
    k_lhist<<<NBLK, 256, 0, stream>>>(rows, ghist, nnz, epb);
    k_rscan<<<NBKT / 4, 256, 0, stream>>>(ghist, btot);
    k_btscan<<<1, 256, 0, stream>>>(btot, bbase);
    k_sscatter<<<NBLK, 256, 0, stream>>>(rows, cols, vals, ghist, bbase, bedges, nnz, epb);
    k_csort<<<NB, 256, 0, stream>>>(bbase, bedges, edges, rowPtr, nnz);

    k_dot<<<(batch + 3) / 4, 256, 0, stream>>>(featb, userIdx, itemIdx, out, batch, 0);

    for (int l = 0; l < NLAYERS; ++l) {
        k_spmm_bf<<<(NN + 3) / 4, 256, 0, stream>>>(rowPtr, edges, featb, Lxb);
        k_layer2<<<(NN + 127) / 128, 256, 0, stream>>>(
            Lxb, Wb4 + (size_t)l * 4096,
            blin + (size_t)l * DD, bint + (size_t)l * DD,
            featb);
        k_dot<<<(batch + 3) / 4, 256, 0, stream>>>(featb, userIdx, itemIdx, out, batch, 1);
    }
}